// Round 1
// baseline (2322.694 us; speedup 1.0000x reference)
//
#include <hip/hip_runtime.h>
#include <math.h>

// Problem constants (B=1)
#define S   2048
#define DK  64
#define DV  64
#define NH  16

// One block per (h, i) query row. 256 threads = 4 waves.
// Phase A: scores + softmax, write attn row.
// Phase B: PV accumulation, write out row.
__global__ __launch_bounds__(256) void attn_row_kernel(
    const float* __restrict__ q,     // [NH, S, DK]
    const float* __restrict__ k,     // [NH, S, DK]
    const float* __restrict__ v,     // [NH, S, DV]
    const float* __restrict__ rpb,   // [NH, S, S]
    float* __restrict__ out,         // [NH, S, DV]
    float* __restrict__ attn)        // [NH, S, S]
{
    const int row = blockIdx.x;          // h*S + i
    const int h   = row >> 11;           // S = 2048
    const int i   = row & (S - 1);
    const int tid = threadIdx.x;
    const int lane = tid & 63;
    const int wid  = tid >> 6;

    __shared__ float s_q[DK];
    __shared__ float s_p[S];             // scores -> probs -> attn
    __shared__ float s_red[4];
    __shared__ float s_acc[4][DV];

    // Load q row into LDS (broadcast source for all dot products)
    if (tid < DK) s_q[tid] = q[(size_t)row * DK + tid];
    __syncthreads();

    const float scale = 0.125f;          // 1/sqrt(64)
    const float* kbase   = k + (size_t)h * S * DK;
    const float* rpb_row = rpb + (size_t)row * S;

    // ---- Phase A1: scores for j in [0, i] ----
    float local_max = -INFINITY;
    for (int j = tid; j <= i; j += 256) {
        const float4* kr = (const float4*)(kbase + (size_t)j * DK);
        float acc = 0.f;
#pragma unroll
        for (int d4 = 0; d4 < DK / 4; ++d4) {
            float4 kv4 = kr[d4];
            acc += s_q[d4 * 4 + 0] * kv4.x;
            acc += s_q[d4 * 4 + 1] * kv4.y;
            acc += s_q[d4 * 4 + 2] * kv4.z;
            acc += s_q[d4 * 4 + 3] * kv4.w;
        }
        float sc = acc * scale + rpb_row[j];
        s_p[j] = sc;
        local_max = fmaxf(local_max, sc);
    }

    // ---- block-reduce max over 256 threads ----
#pragma unroll
    for (int off = 32; off; off >>= 1)
        local_max = fmaxf(local_max, __shfl_down(local_max, off));
    if (lane == 0) s_red[wid] = local_max;
    __syncthreads();
    const float m = fmaxf(fmaxf(s_red[0], s_red[1]), fmaxf(s_red[2], s_red[3]));
    __syncthreads();   // everyone has read s_red before reuse

    // ---- Phase A2: exp + sum ----
    float local_sum = 0.f;
    for (int j = tid; j <= i; j += 256) {
        float p = __expf(s_p[j] - m);
        s_p[j] = p;
        local_sum += p;
    }
#pragma unroll
    for (int off = 32; off; off >>= 1)
        local_sum += __shfl_down(local_sum, off);
    if (lane == 0) s_red[wid] = local_sum;
    __syncthreads();
    const float denom = s_red[0] + s_red[1] + s_red[2] + s_red[3];
    const float inv = 1.0f / denom;

    // ---- Phase A3: normalize, write attn row (zeros past diagonal) ----
    float* arow = attn + (size_t)row * S;
    for (int j = tid; j <= i; j += 256) {
        float a = s_p[j] * inv;
        s_p[j] = a;
        arow[j] = a;
    }
    for (int j = i + 1 + tid; j < S; j += 256) {
        arow[j] = 0.f;
    }
    __syncthreads();

    // ---- Phase B: out[d] = sum_j attn[j] * v[j][d] ----
    const int d = tid & (DV - 1);
    const int g = tid >> 6;              // 4 j-groups
    const float* vb = v + (size_t)h * S * DV + d;
    float acc = 0.f;
    for (int j = g; j <= i; j += 4) {
        acc += s_p[j] * vb[(size_t)j * DV];
    }
    s_acc[g][d] = acc;
    __syncthreads();
    if (tid < DV) {
        out[(size_t)row * DV + tid] =
            s_acc[0][tid] + s_acc[1][tid] + s_acc[2][tid] + s_acc[3][tid];
    }
}

extern "C" void kernel_launch(void* const* d_in, const int* in_sizes, int n_in,
                              void* d_out, int out_size, void* d_ws, size_t ws_size,
                              hipStream_t stream) {
    const float* q   = (const float*)d_in[0];
    const float* k   = (const float*)d_in[1];
    const float* v   = (const float*)d_in[2];
    // d_in[3] is the causal mask (tril) — deterministic, computed from indices.
    const float* rpb = (const float*)d_in[4];

    float* out  = (float*)d_out;                       // [NH,S,DV] = 2,097,152 floats
    float* attn = (float*)d_out + (size_t)NH * S * DV; // [NH,S,S]  = 67,108,864 floats

    dim3 grid(NH * S);
    dim3 block(256);
    attn_row_kernel<<<grid, block, 0, stream>>>(q, k, v, rpb, out, attn);
}

// Round 2
// 269.511 us; speedup vs baseline: 8.6182x; 8.6182x over previous
//
#include <hip/hip_runtime.h>
#include <math.h>

#define S_   2048
#define DK_  64
#define DV_  64
#define NH_  16

typedef __attribute__((ext_vector_type(8))) short bf16x8;
typedef __attribute__((ext_vector_type(4))) float f32x4;

__device__ __forceinline__ unsigned short f2bf_rn(float x){
  unsigned u = __float_as_uint(x);
  u += 0x7fffu + ((u >> 16) & 1u);
  return (unsigned short)(u >> 16);
}
__device__ __forceinline__ float bf2f(unsigned short h){
  return __uint_as_float(((unsigned)h) << 16);
}

#define MFMA16(a,b,c) __builtin_amdgcn_mfma_f32_16x16x32_bf16(a,b,c,0,0,0)

__device__ __forceinline__ void cvt8_split(const float4& a, const float4& b,
                                           bf16x8& hi, bf16x8& lo){
  float xs[8] = {a.x,a.y,a.z,a.w,b.x,b.y,b.z,b.w};
#pragma unroll
  for (int e=0;e<8;++e){
    unsigned short hh = f2bf_rn(xs[e]);
    hi[e] = (short)hh;
    lo[e] = (short)f2bf_rn(xs[e] - bf2f(hh));
  }
}

__global__ __launch_bounds__(256, 4) void attn_mfma_kernel(
    const float* __restrict__ q, const float* __restrict__ k,
    const float* __restrict__ v, const float* __restrict__ rpb,
    float* __restrict__ out, float* __restrict__ attn)
{
  __shared__ short s_kh[64*64];
  __shared__ short s_kl[64*64];
  __shared__ short s_vt[64*64];
  __shared__ short s_p [4*16*64];

  const int bid = blockIdx.x;
  const int h   = bid & 15;
  const int tt  = bid >> 4;
  const int qt  = (bid < 256) ? (31 - tt) : (tt - 16);   // heavy-first, complementary pairs

  const int tid = threadIdx.x;
  const int l   = tid & 63;
  const int w   = tid >> 6;
  const int l15 = l & 15;
  const int l4  = l >> 4;

  const float* kbase = k + (size_t)h * S_ * DK_;
  const float* vbase = v + (size_t)h * S_ * DV_;

  // ---- Q fragments (split bf16), kept in registers ----
  const int qlrow  = w*16 + l15;               // A-operand row within 64-tile
  const int qrow_g = qt*64 + qlrow;
  const float* qp  = q + ((size_t)h*S_ + qrow_g)*DK_;
  bf16x8 qh[2], qlo[2];
#pragma unroll
  for (int ks = 0; ks < 2; ++ks){
    const float* src = qp + ks*32 + l4*8;
    float4 a0 = *(const float4*)(src);
    float4 a1 = *(const float4*)(src+4);
    cvt8_split(a0, a1, qh[ks], qlo[ks]);
  }

  // rpb/attn/out bases for this thread's 4 C-rows (rows l4*4+0..3 of the wave's 16)
  const size_t rowg = (size_t)h*S_ + (size_t)(qt*64 + w*16 + l4*4);
  const float* rp_base = rpb  + rowg*S_ + l15;
  float*       a_base  = attn + rowg*S_ + l15;
  float*       o_base  = out  + rowg*DV_ + l15;

  const int sr = tid >> 2;       // staging row 0..63
  const int sc = tid & 3;        // staging col group 0..3 (16 floats each)

  // =============== PASS 1: row sums of exp(score) ===============
  float esum[4] = {0.f,0.f,0.f,0.f};
  for (int jt = 0; jt <= qt; ++jt){
    // prefetch bias tile for this thread's 16 (n,r) cells
    float rbv[4][4];
#pragma unroll
    for (int n=0;n<4;++n)
#pragma unroll
      for (int r=0;r<4;++r)
        rbv[n][r] = rp_base[(size_t)r*S_ + jt*64 + n*16];

    // stage K tile, split bf16, XOR-swizzled chunks
    {
      const float* kr = kbase + (size_t)(jt*64 + sr)*DK_ + sc*16;
      float4 f0 = ((const float4*)kr)[0];
      float4 f1 = ((const float4*)kr)[1];
      float4 f2 = ((const float4*)kr)[2];
      float4 f3 = ((const float4*)kr)[3];
      bf16x8 h0,l0,h1,l1;
      cvt8_split(f0,f1,h0,l0);
      cvt8_split(f2,f3,h1,l1);
      int o0 = sr*64 + ((2*sc  ) ^ (sr&7))*8;
      int o1 = sr*64 + ((2*sc+1) ^ (sr&7))*8;
      *(bf16x8*)&s_kh[o0] = h0; *(bf16x8*)&s_kl[o0] = l0;
      *(bf16x8*)&s_kh[o1] = h1; *(bf16x8*)&s_kl[o1] = l1;
    }
    __syncthreads();
    const bool diag = (jt == qt);
#pragma unroll
    for (int n=0;n<4;++n){
      f32x4 acc = {0.f,0.f,0.f,0.f};
      const int keyr = n*16 + l15;
#pragma unroll
      for (int ks=0;ks<2;++ks){
        int off = keyr*64 + (((ks*4 + l4) ^ (keyr&7))*8);
        bf16x8 bh = *(const bf16x8*)&s_kh[off];
        bf16x8 bl = *(const bf16x8*)&s_kl[off];
        acc = MFMA16(qh[ks],  bh, acc);
        acc = MFMA16(qlo[ks], bh, acc);
        acc = MFMA16(qh[ks],  bl, acc);
      }
#pragma unroll
      for (int r=0;r<4;++r){
        float scv = acc[r]*0.125f + rbv[n][r];
        bool ok = !diag || (keyr <= w*16 + l4*4 + r);
        esum[r] += ok ? __expf(scv) : 0.f;
      }
    }
    __syncthreads();
  }
  // one reduce at the end: rows are private to 16-lane groups
  float invl[4];
#pragma unroll
  for (int r=0;r<4;++r){
    float e = esum[r];
    e += __shfl_xor(e, 1);
    e += __shfl_xor(e, 2);
    e += __shfl_xor(e, 4);
    e += __shfl_xor(e, 8);
    invl[r] = 1.f / e;
  }

  // =============== PASS 2: attn write + PV ===============
  f32x4 oacc[4];
#pragma unroll
  for (int n=0;n<4;++n) oacc[n] = (f32x4){0.f,0.f,0.f,0.f};

  for (int jt = 0; jt <= qt; ++jt){
    float rbv[4][4];
#pragma unroll
    for (int n=0;n<4;++n)
#pragma unroll
      for (int r=0;r<4;++r)
        rbv[n][r] = rp_base[(size_t)r*S_ + jt*64 + n*16];

    // stage K (split) + V (transposed, single bf16)
    {
      const float* kr = kbase + (size_t)(jt*64 + sr)*DK_ + sc*16;
      float4 f0 = ((const float4*)kr)[0];
      float4 f1 = ((const float4*)kr)[1];
      float4 f2 = ((const float4*)kr)[2];
      float4 f3 = ((const float4*)kr)[3];
      bf16x8 h0,l0,h1,l1;
      cvt8_split(f0,f1,h0,l0);
      cvt8_split(f2,f3,h1,l1);
      int o0 = sr*64 + ((2*sc  ) ^ (sr&7))*8;
      int o1 = sr*64 + ((2*sc+1) ^ (sr&7))*8;
      *(bf16x8*)&s_kh[o0] = h0; *(bf16x8*)&s_kl[o0] = l0;
      *(bf16x8*)&s_kh[o1] = h1; *(bf16x8*)&s_kl[o1] = l1;

      const float* vr = vbase + (size_t)(jt*64 + sr)*DV_ + sc*16;
      float4 g0 = ((const float4*)vr)[0];
      float4 g1 = ((const float4*)vr)[1];
      float4 g2 = ((const float4*)vr)[2];
      float4 g3 = ((const float4*)vr)[3];
      float vals[16] = {g0.x,g0.y,g0.z,g0.w,g1.x,g1.y,g1.z,g1.w,
                        g2.x,g2.y,g2.z,g2.w,g3.x,g3.y,g3.z,g3.w};
#pragma unroll
      for (int e=0;e<16;++e){
        int dv  = sc*16 + e;
        int vsw = (dv ^ (dv>>3)) & 7;
        s_vt[dv*64 + (((sr>>3) ^ vsw)*8) + (sr&7)] = (short)f2bf_rn(vals[e]);
      }
    }
    __syncthreads();
    const bool diag = (jt == qt);
#pragma unroll
    for (int n=0;n<4;++n){
      f32x4 acc = {0.f,0.f,0.f,0.f};
      const int keyr = n*16 + l15;
#pragma unroll
      for (int ks=0;ks<2;++ks){
        int off = keyr*64 + (((ks*4 + l4) ^ (keyr&7))*8);
        bf16x8 bh = *(const bf16x8*)&s_kh[off];
        bf16x8 bl = *(const bf16x8*)&s_kl[off];
        acc = MFMA16(qh[ks],  bh, acc);
        acc = MFMA16(qlo[ks], bh, acc);
        acc = MFMA16(qh[ks],  bl, acc);
      }
#pragma unroll
      for (int r=0;r<4;++r){
        int   rl  = l4*4 + r;
        float scv = acc[r]*0.125f + rbv[n][r];
        bool ok = !diag || (keyr <= w*16 + rl);
        float p = ok ? __expf(scv)*invl[r] : 0.f;
        a_base[(size_t)r*S_ + jt*64 + n*16] = p;
        s_p[w*1024 + rl*64 + (((keyr>>3) ^ (rl&7))*8) + (keyr&7)] = (short)f2bf_rn(p);
      }
    }
    __syncthreads();   // P visible (also covers cross-lane LDS ordering)

    // PV: A = P (row = l15, contiguous keys), B = V^T (col = dv)
    bf16x8 pa[2];
#pragma unroll
    for (int ks=0;ks<2;++ks)
      pa[ks] = *(const bf16x8*)&s_p[w*1024 + l15*64 + (((ks*4 + l4) ^ (l15&7))*8)];
#pragma unroll
    for (int n=0;n<4;++n){
      int dv  = n*16 + l15;
      int vsw = (dv ^ (dv>>3)) & 7;
#pragma unroll
      for (int ks=0;ks<2;++ks){
        bf16x8 vb = *(const bf16x8*)&s_vt[dv*64 + (((ks*4 + l4) ^ vsw)*8)];
        oacc[n] = MFMA16(pa[ks], vb, oacc[n]);
      }
    }
    __syncthreads();
  }

  // write out rows
#pragma unroll
  for (int n=0;n<4;++n)
#pragma unroll
    for (int r=0;r<4;++r)
      o_base[(size_t)r*DV_ + n*16] = oacc[n][r];

  // zero-fill non-causal attn columns for this q-tile
  const int zstart = (qt+1)*64;
  if (zstart < S_){
    const int zr  = tid >> 2;
    const int zc0 = (tid & 3) * 4;
    float* arow = attn + ((size_t)h*S_ + (size_t)(qt*64 + zr))*S_;
    float4 z4 = {0.f,0.f,0.f,0.f};
    for (int col = zstart + zc0; col < S_; col += 16)
      *(float4*)&arow[col] = z4;
  }
}

extern "C" void kernel_launch(void* const* d_in, const int* in_sizes, int n_in,
                              void* d_out, int out_size, void* d_ws, size_t ws_size,
                              hipStream_t stream) {
  const float* q   = (const float*)d_in[0];
  const float* k   = (const float*)d_in[1];
  const float* v   = (const float*)d_in[2];
  // d_in[3]: causal tril mask — deterministic, derived from indices
  const float* rpb = (const float*)d_in[4];

  float* out  = (float*)d_out;                          // [NH,S,DV]
  float* attn = (float*)d_out + (size_t)NH_ * S_ * DV_; // [NH,S,S]

  dim3 grid(NH_ * 32);   // 16 heads x 32 q-tiles (complementary-paired order)
  dim3 block(256);
  attn_mfma_kernel<<<grid, block, 0, stream>>>(q, k, v, rpb, out, attn);
}

// Round 3
// 185.728 us; speedup vs baseline: 12.5059x; 1.4511x over previous
//
#include <hip/hip_runtime.h>
#include <math.h>

#define S_   2048
#define NH_  16

typedef __attribute__((ext_vector_type(8))) short bf16x8;
typedef __attribute__((ext_vector_type(4))) float f32x4;

__device__ __forceinline__ unsigned short f2bf_rn(float x){
  unsigned u = __float_as_uint(x);
  u += 0x7fffu + ((u >> 16) & 1u);
  return (unsigned short)(u >> 16);
}
__device__ __forceinline__ float bf2f(unsigned short h){
  return __uint_as_float(((unsigned)h) << 16);
}

#define MFMA16(a,b,c) __builtin_amdgcn_mfma_f32_16x16x32_bf16(a,b,c,0,0,0)

__device__ __forceinline__ void cvt8_split(const float4& a, const float4& b,
                                           bf16x8& hi, bf16x8& lo){
  float xs[8] = {a.x,a.y,a.z,a.w,b.x,b.y,b.z,b.w};
#pragma unroll
  for (int e=0;e<8;++e){
    unsigned short hh = f2bf_rn(xs[e]);
    hi[e] = (short)hh;
    lo[e] = (short)f2bf_rn(xs[e] - bf2f(hh));
  }
}

// 512 threads = 8 waves. Waves (wr, kh): wr=w&3 -> 16 q-rows, kh=w>>2 -> 32-key half.
// One pass: unnormalized exp -> attn + online esum/PV; post rescale+zero sweep.
__global__ __launch_bounds__(512, 4) void attn_fused_kernel(
    const float* __restrict__ q, const float* __restrict__ k,
    const float* __restrict__ v, const float* __restrict__ rpb,
    float* __restrict__ out, float* __restrict__ attn)
{
  __shared__ short s_kh[2][4096];   // K hi, split bf16, swizzled   (16 KB)
  __shared__ short s_kl[2][4096];   // K lo                          (16 KB)
  __shared__ short s_vt[2][4096];   // V^T bf16, swizzled            (16 KB)
  __shared__ short s_p [8*512];     // per-wave P (16 rows x 32 keys) (8 KB)
  __shared__ float s_esum[2][64];
  __shared__ float s_inv[64];

  const int bid = blockIdx.x;
  const int h   = bid & 15;
  const int tt  = bid >> 4;
  const int qt  = (bid < 256) ? (31 - tt) : (tt - 16);   // heavy-first, complementary pairs

  const int tid = threadIdx.x;
  const int l   = tid & 63;
  const int w   = tid >> 6;     // 0..7
  const int wr  = w & 3;        // q-row group
  const int kh  = w >> 2;       // key half (0: keys 0..31, 1: 32..63)
  const int l15 = l & 15;
  const int l4  = l >> 4;

  const float* kbase = k + (size_t)h * S_ * 64;
  const float* vbase = v + (size_t)h * S_ * 64;

  // ---- Q fragments (split bf16) ----
  const int qrow_g = qt*64 + wr*16 + l15;
  const float* qp  = q + ((size_t)h*S_ + qrow_g)*64;
  bf16x8 qh[2], qlo[2];
#pragma unroll
  for (int ks = 0; ks < 2; ++ks){
    const float* src = qp + ks*32 + l4*8;
    float4 a0 = *(const float4*)(src);
    float4 a1 = *(const float4*)(src+4);
    cvt8_split(a0, a1, qh[ks], qlo[ks]);
  }

  const size_t rowg = (size_t)h*S_ + (size_t)(qt*64 + wr*16 + l4*4);
  const float* rp_base = rpb  + rowg*S_ + l15;
  float*       a_base  = attn + rowg*S_ + l15;

  const int sr = tid >> 3;      // staging row 0..63
  const int sc = tid & 7;       // 8-float chunk 0..7

  auto stage_write = [&](int bb, const float4& a0, const float4& a1,
                         const float4& b0, const float4& b1){
    bf16x8 khi, klo;
    cvt8_split(a0, a1, khi, klo);
    const int ko = sr*64 + ((sc ^ (sr&7))*8);
    *(bf16x8*)&s_kh[bb][ko] = khi;
    *(bf16x8*)&s_kl[bb][ko] = klo;
    float vals[8] = {b0.x,b0.y,b0.z,b0.w,b1.x,b1.y,b1.z,b1.w};
#pragma unroll
    for (int e=0;e<8;++e){
      const int dv  = sc*8 + e;
      const int vsw = (dv ^ (dv>>3)) & 7;
      s_vt[bb][dv*64 + (((sr>>3) ^ vsw)*8) + (sr&7)] = (short)f2bf_rn(vals[e]);
    }
  };

  float esum[4] = {0.f,0.f,0.f,0.f};
  f32x4 oacc[4];
#pragma unroll
  for (int n=0;n<4;++n) oacc[n] = (f32x4){0.f,0.f,0.f,0.f};

  // ---- prologue: stage tile 0 ----
  float4 k0,k1,v0,v1;
  {
    const float* kr = kbase + (size_t)sr*64 + sc*8;
    k0 = ((const float4*)kr)[0]; k1 = ((const float4*)kr)[1];
    const float* vr = vbase + (size_t)sr*64 + sc*8;
    v0 = ((const float4*)vr)[0]; v1 = ((const float4*)vr)[1];
  }
  stage_write(0, k0,k1,v0,v1);
  __syncthreads();

  for (int jt = 0; jt <= qt; ++jt){
    const int  b    = jt & 1;
    const bool more = (jt < qt);
    if (more){   // issue next tile's loads early; latency hides under compute
      const float* kr = kbase + (size_t)((jt+1)*64 + sr)*64 + sc*8;
      k0 = ((const float4*)kr)[0]; k1 = ((const float4*)kr)[1];
      const float* vr = vbase + (size_t)((jt+1)*64 + sr)*64 + sc*8;
      v0 = ((const float4*)vr)[0]; v1 = ((const float4*)vr)[1];
    }
    float rbv[2][4];
#pragma unroll
    for (int n=0;n<2;++n)
#pragma unroll
      for (int r=0;r<4;++r)
        rbv[n][r] = rp_base[(size_t)r*S_ + jt*64 + (kh*2+n)*16];

    const bool diag = (jt == qt);
#pragma unroll
    for (int n=0;n<2;++n){
      f32x4 acc = {0.f,0.f,0.f,0.f};
      const int keyr = (kh*2+n)*16 + l15;        // tile-local key
#pragma unroll
      for (int ks=0;ks<2;++ks){
        const int off = keyr*64 + (((ks*4 + l4) ^ (keyr&7))*8);
        bf16x8 bh = *(const bf16x8*)&s_kh[b][off];
        bf16x8 bl = *(const bf16x8*)&s_kl[b][off];
        acc = MFMA16(qh[ks],  bh, acc);
        acc = MFMA16(qlo[ks], bh, acc);
        acc = MFMA16(qh[ks],  bl, acc);
      }
#pragma unroll
      for (int r=0;r<4;++r){
        const int rl  = l4*4 + r;                 // tile-local q-row
        float scv = acc[r]*0.125f + rbv[n][r];
        bool okm  = !diag || (keyr <= wr*16 + rl);
        float p   = okm ? __expf(scv) : 0.f;
        esum[r] += p;
        a_base[(size_t)r*S_ + jt*64 + (kh*2+n)*16] = p;   // unnormalized
        const int kloc = n*16 + l15;              // key local to half (0..31)
        s_p[w*512 + rl*32 + (((kloc>>3) ^ (rl&3))*8) + (l15&7)] = (short)f2bf_rn(p);
      }
    }
    // PV: s_p is wave-private; same-wave LDS ordering handled by compiler waitcnts
    bf16x8 pa = *(const bf16x8*)&s_p[w*512 + l15*32 + ((l4 ^ (l15&3))*8)];
#pragma unroll
    for (int n2=0;n2<4;++n2){
      const int dv  = n2*16 + l15;
      const int vsw = (dv ^ (dv>>3)) & 7;
      bf16x8 vb = *(const bf16x8*)&s_vt[b][dv*64 + (((kh*4+l4) ^ vsw)*8)];
      oacc[n2] = MFMA16(pa, vb, oacc[n2]);
    }
    if (more) stage_write(b^1, k0,k1,v0,v1);
    __syncthreads();
  }

  // ---- esum combine across l15 then across key halves ----
  float ered[4];
#pragma unroll
  for (int r=0;r<4;++r){
    float e = esum[r];
    e += __shfl_xor(e, 1);
    e += __shfl_xor(e, 2);
    e += __shfl_xor(e, 4);
    e += __shfl_xor(e, 8);
    ered[r] = e;
  }
  if (l15 == 0){
#pragma unroll
    for (int r=0;r<4;++r) s_esum[kh][wr*16 + l4*4 + r] = ered[r];
  }
  __syncthreads();

  float inv4[4];
#pragma unroll
  for (int r=0;r<4;++r){
    const int row = wr*16 + l4*4 + r;
    inv4[r] = 1.0f / (s_esum[0][row] + s_esum[1][row]);
  }
  if (kh == 0 && l15 == 0){
#pragma unroll
    for (int r=0;r<4;++r) s_inv[wr*16 + l4*4 + r] = inv4[r];
  }

  // ---- oacc combine (kh=1 partials via LDS, reuse K buffers) ----
  float* s_oc = (float*)&s_kh[0][0];             // 64x64 f32 = 16 KB
  if (kh == 1){
#pragma unroll
    for (int n2=0;n2<4;++n2)
#pragma unroll
      for (int r=0;r<4;++r)
        s_oc[(wr*16 + l4*4 + r)*64 + n2*16 + l15] = oacc[n2][r];
  }
  __syncthreads();

  if (kh == 0){
    float* o_base = out + ((size_t)h*S_ + qt*64 + wr*16 + l4*4)*64 + l15;
#pragma unroll
    for (int n2=0;n2<4;++n2)
#pragma unroll
      for (int r=0;r<4;++r)
        o_base[(size_t)r*64 + n2*16] =
            (oacc[n2][r] + s_oc[(wr*16 + l4*4 + r)*64 + n2*16 + l15]) * inv4[r];
  }

  // ---- rescale + zero sweep over this block's 64 attn rows ----
  // (attn stores drained to L2 by the syncthreads' vmcnt(0); s_inv covered by sync)
  const int srow = tid >> 3;        // 0..63
  const int t8   = tid & 7;
  const int ig   = qt*64 + srow;    // global row index
  float* arow = attn + ((size_t)h*S_ + ig)*S_;
  const float rinv = s_inv[srow];
  float4 z4 = {0.f,0.f,0.f,0.f};
  for (int c = t8; c < 512; c += 8){
    const int c0 = c*4;
    float4* p4 = (float4*)&arow[c0];
    if (c0 + 3 <= ig){
      float4 t = *p4;
      t.x *= rinv; t.y *= rinv; t.z *= rinv; t.w *= rinv;
      *p4 = t;
    } else if (c0 > ig){
      *p4 = z4;
    } else {
      float4 t = *p4;
      t.x = (c0   <= ig) ? t.x*rinv : 0.f;
      t.y = (c0+1 <= ig) ? t.y*rinv : 0.f;
      t.z = (c0+2 <= ig) ? t.z*rinv : 0.f;
      t.w = (c0+3 <= ig) ? t.w*rinv : 0.f;
      *p4 = t;
    }
  }
}

extern "C" void kernel_launch(void* const* d_in, const int* in_sizes, int n_in,
                              void* d_out, int out_size, void* d_ws, size_t ws_size,
                              hipStream_t stream) {
  const float* q   = (const float*)d_in[0];
  const float* k   = (const float*)d_in[1];
  const float* v   = (const float*)d_in[2];
  // d_in[3]: causal tril mask — deterministic, derived from indices
  const float* rpb = (const float*)d_in[4];

  float* out  = (float*)d_out;                          // [NH,S,DV]
  float* attn = (float*)d_out + (size_t)NH_ * S_ * 64;  // [NH,S,S]

  dim3 grid(NH_ * 32);
  dim3 block(512);
  attn_fused_kernel<<<grid, block, 0, stream>>>(q, k, v, rpb, out, attn);
}